// Round 6
// baseline (982.297 us; speedup 1.0000x reference)
//
#include <hip/hip_runtime.h>
#include <math.h>

#define B_ 8
#define P_ 8192
#define N_ 65536
#define K_ 16
#define EPS_ 1e-5f
#define NBK 1024                 // x-buckets per batch
#define BSCALE 20.48f            // NBK / 50.0

// ============================ binning ======================================
__global__ __launch_bounds__(256) void init_bins(int* counts, int* cursors,
                                                 int* xminI, int* xmaxI) {
    int i = blockIdx.x * 256 + threadIdx.x;   // 8192 entries
    counts[i] = 0; cursors[i] = 0;
    xminI[i] = 0x7F7FFFFF;                    // +FLT_MAX bits (x >= 0 -> int order == float order)
    xmaxI[i] = 0x80000000;                    // < any non-negative float's bits
}

__device__ __forceinline__ int bucket_of(float x) {
    int b = (int)(x * BSCALE);
    return b > (NBK - 1) ? (NBK - 1) : (b < 0 ? 0 : b);
}

__global__ __launch_bounds__(256) void count_kernel(const float* __restrict__ vc,
                                                    int* counts, int* xminI, int* xmaxI) {
    int q = blockIdx.x * 256 + threadIdx.x;
    float4 p = ((const float4*)vc)[q];        // [batch, x, y, z]
    int b = q >> 13;
    int bk = bucket_of(p.y);
    int e = b * NBK + bk;
    atomicAdd(&counts[e], 1);
    int xb = __float_as_int(p.y);
    atomicMin(&xminI[e], xb);
    atomicMax(&xmaxI[e], xb);
}

__global__ __launch_bounds__(1024) void scan_kernel(const int* __restrict__ counts,
                                                    const int* __restrict__ xminI,
                                                    const int* __restrict__ xmaxI,
                                                    int* off, float* xlub, float* xglb) {
    __shared__ int   smi[NBK];
    __shared__ float smf[NBK];
    int b = blockIdx.x, t = threadIdx.x;
    int e = b * NBK + t;

    int c = counts[e];
    smi[t] = c; __syncthreads();
    for (int s = 1; s < NBK; s <<= 1) {
        int u = smi[t]; int v = (t >= s) ? smi[t - s] : 0;
        __syncthreads(); smi[t] = u + v; __syncthreads();
    }
    off[b * (NBK + 1) + t] = smi[t] - c;
    if (t == NBK - 1) off[b * (NBK + 1) + NBK] = smi[t];

    float mx = c ? __int_as_float(xmaxI[e]) : -1e30f;
    smf[t] = mx; __syncthreads();
    for (int s = 1; s < NBK; s <<= 1) {
        float u = smf[t]; float v = (t >= s) ? smf[t - s] : -1e30f;
        __syncthreads(); smf[t] = fmaxf(u, v); __syncthreads();
    }
    xlub[e] = smf[t];
    __syncthreads();

    int r = NBK - 1 - t;
    int cr_ = counts[b * NBK + r];
    float mn = cr_ ? __int_as_float(xminI[b * NBK + r]) : 1e30f;
    smf[t] = mn; __syncthreads();
    for (int s = 1; s < NBK; s <<= 1) {
        float u = smf[t]; float v = (t >= s) ? smf[t - s] : 1e30f;
        __syncthreads(); smf[t] = fminf(u, v); __syncthreads();
    }
    xglb[b * NBK + r] = smf[t];
}

__global__ __launch_bounds__(256) void scatter_kernel(const float* __restrict__ vc,
                                                      const int* __restrict__ off,
                                                      int* cursors, float4* pos4s) {
    int q = blockIdx.x * 256 + threadIdx.x;
    float4 p = ((const float4*)vc)[q];
    int b = q >> 13;
    int bk = bucket_of(p.y);
    int slot = off[b * (NBK + 1) + bk] + atomicAdd(&cursors[b * NBK + bk], 1);
    pos4s[(b << 13) + slot] = make_float4(p.y, p.z, p.w, __int_as_float(q));
}

// ============================ knn (single-pass, 2 threads/query) ===========
// Block = 128 consecutive x-sorted queries; thread pair (tid, tid^128) splits
// every tile's slots by parity. Hot loop: 4-candidate chunks (load ILP), a
// register min/max network maintains own-stream bd15; hits (d <= tbound,
// tbound = min(pair bd15) >= final tau) recorded to per-thread LDS buffer
// (cap 32, exact compaction). Final per-query merge through a u64 lex network
// on (d_bits<<32 | idx) reproduces top_k's lowest-index tie-break exactly.
__global__ __launch_bounds__(256) void knn4_kernel(const float4* __restrict__ pos4s,
                                                   const float* __restrict__ xlub,
                                                   const float* __restrict__ xglb,
                                                   unsigned short* __restrict__ idx_out,
                                                   float* __restrict__ d2_out) {
    const int tid   = threadIdx.x;
    const int sub   = tid >> 7;                   // 0/1: parity of tile slots
    const int bb    = blockIdx.x >> 6;            // batch (64 blocks/batch)
    const int bbase = bb << 13;
    const int home0 = bbase + ((blockIdx.x & 63) << 7);
    const int qslot = home0 + (tid & 127);
    const float4 me = pos4s[qslot];
    const float qx = me.x, qy = me.y, qz = me.z;
    const int q = __float_as_int(me.w);
    const float* xl = xlub + (bb << 10);
    const float* xg = xglb + (bb << 10);

    __shared__ __align__(16) float4 tile[256];    // 4 KB
    __shared__ float2 hb[256 * 33];               // 66 KB (stride 33: bank spread)
    __shared__ float bd15s[256];
    __shared__ int   cnts[256];
    __shared__ int   sflags[2];

    const int hbase = tid * 33;
    float bd[K_];
#pragma unroll
    for (int t = 0; t < K_; ++t) bd[t] = __builtin_huge_valf();
    float bd15   = __builtin_huge_valf();
    float tbound = __builtin_huge_valf();
    int cnt = 0;

#define DIST_(c, dd)                                                        \
    float dd; {                                                             \
        float dx = __fsub_rn(qx, (c).x);                                    \
        float dy = __fsub_rn(qy, (c).y);                                    \
        float dz = __fsub_rn(qz, (c).z);                                    \
        dd = __fadd_rn(__fadd_rn(__fmul_rn(dx,dx), __fmul_rn(dy,dy)),       \
                       __fmul_rn(dz,dz));                                   \
    }

#define PROC_(d, c) {                                                       \
        if (d < bd15) {                                                     \
            _Pragma("unroll")                                               \
            for (int t = K_-1; t > 0; --t)                                  \
                bd[t] = fminf(bd[t], fmaxf(bd[t-1], d));                    \
            bd[0] = fminf(bd[0], d);                                        \
            bd15 = bd[K_-1];                                                \
        }                                                                   \
        float rt = fminf(tbound, bd15);                                     \
        if (d <= rt) {                                                      \
            if (cnt >= 32) {          /* exact compaction: keep d <= rt */  \
                int w = 0;                                                  \
                for (int t2 = 0; t2 < 32; ++t2) {                           \
                    float2 e = hb[hbase + t2];                              \
                    if (e.x <= rt) { hb[hbase + w] = e; ++w; }              \
                }                                                           \
                cnt = w;                                                    \
            }                                                               \
            hb[hbase + cnt] = make_float2(d, (c).w);                        \
            ++cnt;                                                          \
        }                                                                   \
    }

    // cntT is always 128 or 256 -> per-thread count divisible by 4: chunk by 8
#define SCAN_T(base, cntT) {                                                \
    __syncthreads();                                                        \
    if (tid < (cntT)) tile[tid] = pos4s[(base) + tid];                      \
    __syncthreads();                                                        \
    for (int jb = 0; jb < (cntT); jb += 8) {                                \
        float4 c0 = tile[jb + sub    ];                                     \
        float4 c1 = tile[jb + sub + 2];                                     \
        float4 c2 = tile[jb + sub + 4];                                     \
        float4 c3 = tile[jb + sub + 6];                                     \
        DIST_(c0, d0) DIST_(c1, d1) DIST_(c2, d2) DIST_(c3, d3)             \
        PROC_(d0, c0) PROC_(d1, c1) PROC_(d2, c2) PROC_(d3, c3)             \
    } }

    // ---- home tile, then center-outward expansion ----
    SCAN_T(home0, 128)
    int sL = home0, sR = home0 + 128;
    for (;;) {
        bd15s[tid] = bd15;
        if (tid == 0) { sflags[0] = 0; sflags[1] = 0; }
        __syncthreads();
        tbound = fminf(bd15, bd15s[tid ^ 128]);
        bool needL = false, needR = false;
        if (sL > bbase) {
            float xb = xl[bucket_of(pos4s[sL - 1].x)];   // ub on x of slots < sL
            float t = __fsub_rn(qx, xb);
            needL = __fmul_rn(t, t) <= tbound;           // non-strict: tie-safe
        }
        if (sR < bbase + P_) {
            float xb = xg[bucket_of(pos4s[sR].x)];       // lb on x of slots >= sR
            float t = __fsub_rn(xb, qx);
            needR = __fmul_rn(t, t) <= tbound;
        }
        if (needL) sflags[0] = 1;
        if (needR) sflags[1] = 1;
        __syncthreads();
        int aL = sflags[0], aR = sflags[1];
        if (!aL && !aR) break;
        if (aL) { int c_ = min(256, sL - bbase);       SCAN_T(sL - c_, c_) sL -= c_; }
        if (aR) { int c_ = min(256, bbase + P_ - sR);  SCAN_T(sR, c_)      sR += c_; }
    }

    // ---- final per-query merge: u64 lex network over the pair's buffers ----
    cnts[tid] = cnt;
    __syncthreads();
    if (sub == 0) {
        unsigned long long kk[K_];
#pragma unroll
        for (int t = 0; t < K_; ++t) kk[t] = ~0ull;
        int c0 = cnt, c1 = cnts[tid + 128];
        int pbase = (tid + 128) * 33;
        for (int j = 0; j < c0; ++j) {
            float2 e = hb[hbase + j];
            unsigned long long key = ((unsigned long long)__float_as_uint(e.x) << 32)
                                   | (unsigned)__float_as_int(e.y);
            if (key < kk[K_-1]) {
#pragma unroll
                for (int t = K_-1; t > 0; --t) {
                    unsigned long long hi = kk[t-1] > key ? kk[t-1] : key;
                    kk[t] = kk[t] < hi ? kk[t] : hi;
                }
                kk[0] = kk[0] < key ? kk[0] : key;
            }
        }
        for (int j = 0; j < c1; ++j) {
            float2 e = hb[pbase + j];
            unsigned long long key = ((unsigned long long)__float_as_uint(e.x) << 32)
                                   | (unsigned)__float_as_int(e.y);
            if (key < kk[K_-1]) {
#pragma unroll
                for (int t = K_-1; t > 0; --t) {
                    unsigned long long hi = kk[t-1] > key ? kk[t-1] : key;
                    kk[t] = kk[t] < hi ? kk[t] : hi;
                }
                kk[0] = kk[0] < key ? kk[0] : key;
            }
        }
#pragma unroll
        for (int t = 0; t < K_; ++t) {
            idx_out[(size_t)q * K_ + t] = (unsigned short)(kk[t] & 0xffffu);
            d2_out[(size_t)q * K_ + t]  = __uint_as_float((unsigned)(kk[t] >> 32));
        }
    }
#undef SCAN_T
#undef PROC_
#undef DIST_
}

// ============================ edgeconv (unchanged) =========================
static __device__ inline double shfl_xor_dbl(double v, int mask) {
    long long b = __double_as_longlong(v);
    int lo = (int)(b & 0xffffffffLL);
    int hi = (int)(b >> 32);
    lo = __shfl_xor(lo, mask, 64);
    hi = __shfl_xor(hi, mask, 64);
    return __longlong_as_double(((long long)hi << 32) | (unsigned long long)(unsigned int)lo);
}

template<int CIN, int COUT, bool PHA>
__global__ __launch_bounds__(256) void edge_kernel(
    const float* __restrict__ x,
    const unsigned short* __restrict__ idx,
    const float* __restrict__ d2,
    const float* __restrict__ W,
    const float* __restrict__ bias,
    const float* __restrict__ wk,
    const float* __restrict__ wq,
    const float* __restrict__ acoef,
    const float* __restrict__ ccoef,
    double* __restrict__ gsum,
    double* __restrict__ gsumsq,
    float* __restrict__ out,
    int niter)
{
    constexpr int LOGC = (COUT == 64) ? 6 : 5;
    constexpr int GPW  = 64 / COUT;
    constexpr int GPB  = 4 * GPW;
    constexpr int C4   = CIN / 4;
    constexpr int SJ   = (K_ + 1) * CIN;
    constexpr int HTS  = COUT + 1;
    constexpr int HTN  = PHA ? 1 : (K_ * HTS);
    constexpr int PN   = PHA ? 1 : (K_ * K_);
    constexpr int KQN  = PHA ? 1 : (2 * K_);
    constexpr int SCN  = PHA ? 1 : K_;
    constexpr int PARTN= (!PHA && COUT == 64) ? 64 : 1;
    constexpr int WKQN = PHA ? 1 : (2 * COUT);

    const int tid  = threadIdx.x;
    const int wave = tid >> 6;
    const int lane = tid & 63;
    const int lo   = lane & (COUT - 1);
    const int grp  = lane >> LOGC;
    const int gidx = wave * GPW + grp;

    __shared__ __align__(16) float sj_s[GPB][SJ];
    __shared__ __align__(16) float hT_s[GPB][HTN];
    __shared__ __align__(16) float p_s[GPB][PN];
    __shared__ __align__(16) float kqv_s[GPB][KQN];
    __shared__ __align__(16) float rden_s[GPB][SCN];
    __shared__ __align__(16) float scal_s[GPB][SCN];
    __shared__ __align__(16) float part_s[GPB][PARTN];
    __shared__ __align__(16) float wkq_s[WKQN];

    float Wr[CIN], Ad[CIN];
#pragma unroll
    for (int c = 0; c < CIN; ++c) {
        float wl = W[lo * (2*CIN) + c];
        float wr = W[lo * (2*CIN) + CIN + c];
        Wr[c] = wr; Ad[c] = wl - wr;
    }
    const float b_s = bias[lo];

    float a_s = 0.f, c_s = 0.f;
    if constexpr (!PHA) {
        a_s = acoef[lo]; c_s = ccoef[lo];
        if (tid < COUT)            wkq_s[tid] = wk[tid];
        else if (tid < 2*COUT)     wkq_s[tid] = wq[tid - COUT];
    }
    __syncthreads();

    double lsum = 0.0, lsq = 0.0;
    const int g0      = blockIdx.x * GPB + gidx;
    const int gstride = gridDim.x * GPB;

    for (int it = 0; it < niter; ++it) {
        const int n = g0 + it * gstride;

        {
            const float4* xs  = (const float4*)x;
            float4*       sj4 = (float4*)sj_s[gidx];
            constexpr int TOT4 = (K_ + 1) * C4;
#pragma unroll
            for (int e0 = 0; e0 < TOT4; e0 += COUT) {
                int e = e0 + lo;
                if (e < TOT4) {
                    int r = e / C4;
                    int c = e - r * C4;
                    int row = (r < K_) ? (int)idx[n * K_ + r] : n;
                    sj4[e] = xs[row * C4 + c];
                }
            }
        }
        if constexpr (!PHA) {
            if (lo < K_) {
                float dis = sqrtf(d2[n * K_ + lo]);
                float e = __expf(-dis);
                scal_s[gidx][lo] = 2.0f * e / (1.0f + e);
            }
        }
        __syncthreads();

        const float* sj = sj_s[gidx];
        float t0 = b_s;
#pragma unroll
        for (int c = 0; c < C4; ++c) {
            float4 v = ((const float4*)(sj + K_ * CIN))[c];
            t0 = fmaf(Ad[4*c  ], v.x, t0);
            t0 = fmaf(Ad[4*c+1], v.y, t0);
            t0 = fmaf(Ad[4*c+2], v.z, t0);
            t0 = fmaf(Ad[4*c+3], v.w, t0);
        }
        float hn[K_];
#pragma unroll
        for (int k = 0; k < K_; ++k) {
            float acc = t0;
            const float4* xr = (const float4*)(sj + k * CIN);
#pragma unroll
            for (int c = 0; c < C4; ++c) {
                float4 v = xr[c];
                acc = fmaf(Wr[4*c  ], v.x, acc);
                acc = fmaf(Wr[4*c+1], v.y, acc);
                acc = fmaf(Wr[4*c+2], v.z, acc);
                acc = fmaf(Wr[4*c+3], v.w, acc);
            }
            float h = fmaxf(acc, 0.f);
            if constexpr (PHA) {
                double hd = (double)h;
                lsum += hd;
                lsq  = fma(hd, hd, lsq);
            } else {
                hn[k] = fmaf(a_s, h, c_s);
            }
        }

        if constexpr (!PHA) {
            float* hT = hT_s[gidx];
#pragma unroll
            for (int k = 0; k < K_; ++k) hT[k * HTS + lo] = hn[k];
            __syncthreads();

            const int kk   = lo & 15;
            const int role = lo >> 4;
            float av = 0.f;
            const float* hrow = hT + kk * HTS;
            int obase; const float* wv;
            if constexpr (COUT == 64) { obase = (role & 1) * 32; wv = wkq_s + ((role >> 1) ? COUT : 0); }
            else                      { obase = 0;               wv = wkq_s + (role ? COUT : 0); }
#pragma unroll
            for (int j = 0; j < 32; ++j)
                av = fmaf(hrow[obase + j], wv[obase + j], av);
            if constexpr (COUT == 64) {
                part_s[gidx][lo] = av;
                __syncthreads();
                if (lo < 16)      kqv_s[gidx][lo] = part_s[gidx][lo]      + part_s[gidx][lo + 16];
                else if (lo < 32) kqv_s[gidx][lo] = part_s[gidx][lo + 16] + part_s[gidx][lo + 32];
            } else {
                kqv_s[gidx][lo] = av;
            }
            __syncthreads();

            if (lo < K_) {
                const int qq = lo;
                const float qv = kqv_s[gidx][K_ + qq];
                float m = -__builtin_huge_valf();
#pragma unroll
                for (int k = 0; k < K_; ++k) m = fmaxf(m, kqv_s[gidx][k] * qv);
                float den = 0.f;
#pragma unroll
                for (int k = 0; k < K_; ++k) {
                    float e = __expf(kqv_s[gidx][k] * qv - m);
                    den += e;
                    p_s[gidx][k * K_ + qq] = e;
                }
                rden_s[gidx][qq] = 1.0f / den;
            }
            __syncthreads();

            float hq[K_];
#pragma unroll
            for (int qq = 0; qq < K_; ++qq) hq[qq] = 0.f;
#pragma unroll
            for (int k = 0; k < K_; ++k) {
                const float hnk = hn[k];
                const float4* p4 = (const float4*)(p_s[gidx] + k * K_);
#pragma unroll
                for (int j = 0; j < 4; ++j) {
                    float4 v = p4[j];
                    hq[4*j  ] = fmaf(hnk, v.x, hq[4*j  ]);
                    hq[4*j+1] = fmaf(hnk, v.y, hq[4*j+1]);
                    hq[4*j+2] = fmaf(hnk, v.z, hq[4*j+2]);
                    hq[4*j+3] = fmaf(hnk, v.w, hq[4*j+3]);
                }
            }
            float res = -__builtin_huge_valf();
#pragma unroll
            for (int j = 0; j < 4; ++j) {
                float4 sc = ((const float4*)scal_s[gidx])[j];
                float4 rd = ((const float4*)rden_s[gidx])[j];
                res = fmaxf(res, sc.x * (hq[4*j  ] * rd.x));
                res = fmaxf(res, sc.y * (hq[4*j+1] * rd.y));
                res = fmaxf(res, sc.z * (hq[4*j+2] * rd.z));
                res = fmaxf(res, sc.w * (hq[4*j+3] * rd.w));
            }
            out[n * COUT + lo] = res;
            __syncthreads();
        } else {
            __syncthreads();
        }
    }

    if constexpr (PHA) {
        if constexpr (COUT == 32) {
            lsum += shfl_xor_dbl(lsum, 32);
            lsq  += shfl_xor_dbl(lsq, 32);
        }
        __shared__ double redS[4][COUT];
        __shared__ double redQ[4][COUT];
        if (lane < COUT) { redS[wave][lane] = lsum; redQ[wave][lane] = lsq; }
        __syncthreads();
        if (tid < COUT) {
            double ss = redS[0][tid] + redS[1][tid] + redS[2][tid] + redS[3][tid];
            double qq = redQ[0][tid] + redQ[1][tid] + redQ[2][tid] + redQ[3][tid];
            atomicAdd(&gsum[tid], ss);
            atomicAdd(&gsumsq[tid], qq);
        }
    }
}

__global__ void finalize_kernel(const double* __restrict__ gsum, const double* __restrict__ gsumsq,
                                const float* __restrict__ gamma, const float* __restrict__ beta,
                                float* __restrict__ a, float* __restrict__ c, int cout)
{
    int o = threadIdx.x;
    if (o < cout) {
        const double inv = 1.0 / ((double)N_ * (double)K_);
        double mu  = gsum[o] * inv;
        double var = gsumsq[o] * inv - mu * mu;
        double rs  = 1.0 / sqrt(var + (double)EPS_);
        double av  = rs * (double)gamma[o];
        a[o] = (float)av;
        c[o] = (float)((double)beta[o] - mu * av);
    }
}

__global__ __launch_bounds__(256) void copy_vc(const float4* __restrict__ src,
                                               float4* __restrict__ dst) {
    int i = blockIdx.x * 256 + threadIdx.x;
    dst[i] = src[i];
}

extern "C" void kernel_launch(void* const* d_in, const int* in_sizes, int n_in,
                              void* d_out, int out_size, void* d_ws, size_t ws_size,
                              hipStream_t stream)
{
    const float* pillar = (const float*)d_in[0];
    const float* vc     = (const float*)d_in[1];
    const float* W0  = (const float*)d_in[2];
    const float* b0  = (const float*)d_in[3];
    const float* g0  = (const float*)d_in[4];
    const float* be0 = (const float*)d_in[5];
    const float* wk0 = (const float*)d_in[6];
    const float* wq0 = (const float*)d_in[7];
    const float* W1  = (const float*)d_in[8];
    const float* b1  = (const float*)d_in[9];
    const float* g1  = (const float*)d_in[10];
    const float* be1 = (const float*)d_in[11];
    const float* wk1 = (const float*)d_in[12];
    const float* wq1 = (const float*)d_in[13];

    // ---- workspace (< 16 MiB total) ----
    char* ws = (char*)d_ws;
    double* dsum = (double*)ws;                              // 2 KB @ 0
    double *s0 = dsum, *sq0 = dsum + 64, *s1 = dsum + 128, *sq1 = dsum + 192;
    float* coef = (float*)(ws + 4096);                       // 1 KB @ 4K
    float *a0 = coef, *c0 = coef + 64, *a1 = coef + 128, *c1 = coef + 192;
    unsigned short* idx = (unsigned short*)(ws + 8192);      // 2 MB
    float* d2  = (float*)(ws + 8192 + (size_t)N_*K_*2);      // 4 MB
    float* x1  = (float*)(ws + 8192 + (size_t)N_*K_*6);      // 8 MB
    size_t base2 = 8192 + (size_t)N_*K_*6 + (size_t)N_*32*4; // = 14 MB + 8 KB
    float4* pos4s = (float4*)(ws + base2);                   // 1 MB
    int* counts   = (int*)(ws + base2 + (1u<<20));           // 32 KB
    int* cursors  = counts + B_*NBK;                         // 32 KB
    int* off      = cursors + B_*NBK;                        // 8*1025*4
    int* xminI    = off + B_*(NBK+1);                        // 32 KB
    int* xmaxI    = xminI + B_*NBK;                          // 32 KB
    float* xlub   = (float*)(xmaxI + B_*NBK);                // 32 KB
    float* xglb   = xlub + B_*NBK;                           // 32 KB

    float* xout = (float*)d_out;
    float* vout = xout + (size_t)N_ * 64;

    hipMemsetAsync(dsum, 0, 2048, stream);
    init_bins<<<B_*NBK/256, 256, 0, stream>>>(counts, cursors, xminI, xmaxI);
    count_kernel<<<N_/256, 256, 0, stream>>>(vc, counts, xminI, xmaxI);
    scan_kernel<<<B_, NBK, 0, stream>>>(counts, xminI, xmaxI, off, xlub, xglb);
    scatter_kernel<<<N_/256, 256, 0, stream>>>(vc, off, cursors, pos4s);
    knn4_kernel<<<N_/128, 256, 0, stream>>>(pos4s, xlub, xglb, idx, d2);

    edge_kernel<4,32,true ><<<1024, 256, 0, stream>>>(pillar, idx, d2, W0, b0, wk0, wq0,
                                                      nullptr, nullptr, s0, sq0, nullptr, 8);
    finalize_kernel<<<1, 64, 0, stream>>>(s0, sq0, g0, be0, a0, c0, 32);
    edge_kernel<4,32,false><<<1024, 256, 0, stream>>>(pillar, idx, d2, W0, b0, wk0, wq0,
                                                      a0, c0, nullptr, nullptr, x1, 8);

    edge_kernel<32,64,true ><<<2048, 256, 0, stream>>>(x1, idx, d2, W1, b1, wk1, wq1,
                                                       nullptr, nullptr, s1, sq1, nullptr, 8);
    finalize_kernel<<<1, 64, 0, stream>>>(s1, sq1, g1, be1, a1, c1, 64);
    edge_kernel<32,64,false><<<2048, 256, 0, stream>>>(x1, idx, d2, W1, b1, wk1, wq1,
                                                       a1, c1, nullptr, nullptr, xout, 8);

    copy_vc<<<256, 256, 0, stream>>>((const float4*)vc, (float4*)vout);
}